// Round 7
// baseline (4672.604 us; speedup 1.0000x reference)
//
#include <hip/hip_runtime.h>
#include <hip/hip_bf16.h>
#include <cstdint>

typedef __attribute__((ext_vector_type(8))) short short8;
typedef __attribute__((ext_vector_type(4))) float f32x4;
typedef unsigned short ushortT;

#define SEQ 200
#define NB  256

__device__ __forceinline__ float b2f(ushortT u){
    union { unsigned u; float f; } v; v.u = ((unsigned)u) << 16; return v.f;
}
__device__ __forceinline__ ushortT f2b(float f){
    union { float f; unsigned u; } v; v.f = f;
    unsigned r = v.u + 0x7FFFu + ((v.u >> 16) & 1u);
    return (ushortT)(r >> 16);
}
// fast reciprocal: ~1 ulp, far below bf16 rounding; avoids the full div sequence
__device__ __forceinline__ float frcp(float x){
    float r; asm("v_rcp_f32 %0, %1" : "=v"(r) : "v"(x)); return r;
}
__device__ __forceinline__ float sigm(float x){ return frcp(1.0f + __expf(-x)); }
__device__ __forceinline__ float tanh_fast(float x){
    float ax = fabsf(x);
    float t = __expf(-2.0f * ax);
    float r = (1.0f - t) * frcp(1.0f + t);
    return copysignf(r, x);
}
// 16B agent-scope load/store as 2x u64 relaxed atomics (cross-XCD safe)
__device__ __forceinline__ short8 ld_frag16(const ushortT* p){
    const unsigned long long* s = (const unsigned long long*)p;
    union { short8 v; unsigned long long u[2]; } r;
    r.u[0] = __hip_atomic_load(s+0, __ATOMIC_RELAXED, __HIP_MEMORY_SCOPE_AGENT);
    r.u[1] = __hip_atomic_load(s+1, __ATOMIC_RELAXED, __HIP_MEMORY_SCOPE_AGENT);
    return r.v;
}

// ---- f32 -> bf16 bulk convert (n multiple of 1024) ----
__global__ void k_cvt(const float* __restrict__ in, ushortT* __restrict__ out){
    size_t i = ((size_t)blockIdx.x*256 + threadIdx.x)*4;
    float4 v = *(const float4*)(in + i);
    ushortT o[4] = { f2b(v.x), f2b(v.y), f2b(v.z), f2b(v.w) };
    *(int2*)(out + i) = *(int2*)o;
}

// ---- swizzle a (K x ncols) f32 row-major matrix into bf16 MFMA B-fragment tiles ----
// tile T (16 cols), kstep q (32 k): lane l holds B[k = q*32+(l>>4)*8+j][n = T*16+(l&15)], j=0..7
__global__ void k_swizzle(const float* __restrict__ src, int ncols,
                          ushortT* __restrict__ dst, int tile0){
    int Tl = blockIdx.x, q = blockIdx.y, l = threadIdx.x;
    int n  = Tl*16 + (l & 15);
    int kb = q*32 + (l >> 4)*8;
    short8 v;
    #pragma unroll
    for (int j = 0; j < 8; ++j) ((ushortT*)&v)[j] = f2b(src[(size_t)(kb + j)*ncols + n]);
    *(short8*)(dst + ((size_t)(tile0 + Tl)*8 + q)*512 + (size_t)l*8) = v;
}

// ---- tft = 1 - tanh((t/180*selw+selb)^2), stored as scan A-fragments (bf16) ----
__global__ void k_tft(const float* __restrict__ sts, const float* __restrict__ selw,
                      const float* __restrict__ selb, ushortT* __restrict__ tft){
    int l = threadIdx.x, g = blockIdx.x / SEQ, t = blockIdx.x % SEQ;
    int lm = l & 15, lq = l >> 4;
    float tv = sts[(size_t)(g*16 + lm)*SEQ + t] * (1.0f/180.0f);
    size_t base = (size_t)(g*SEQ + t)*1024 + (size_t)l*8;
    #pragma unroll
    for (int q = 0; q < 2; ++q){
        short8 v;
        #pragma unroll
        for (int j = 0; j < 8; ++j){
            int u = q*32 + lq*8 + j;
            float a = tv * selw[u] + selb[u];
            ((ushortT*)&v)[j] = f2b(1.0f - tanh_fast(a*a));
        }
        *(short8*)(tft + base + (size_t)q*512) = v;
    }
}

// ---- generic C[rows x 256] = A[rows x 256] @ Bswz(16 tiles) + bias(f32), bf16 out ----
__global__ __launch_bounds__(512) void k_gemm256(const ushortT* A,
        const ushortT* __restrict__ Bswz, const float* __restrict__ bias, ushortT* out){
    __shared__ ushortT stage[16*256];
    int tid = threadIdx.x, w = tid >> 6, l = tid & 63, lm = l & 15, lq = l >> 4;
    size_t r0 = (size_t)blockIdx.x * 16;
    const f32x4 fz = {0.f,0.f,0.f,0.f};
    f32x4 acc[2] = {fz, fz};
    for (int q = 0; q < 8; ++q){
        short8 a = *(const short8*)(A + (r0 + lm)*256 + q*32 + lq*8);
        #pragma unroll
        for (int p = 0; p < 2; ++p){
            int T = 2*w + p;
            short8 b = *(const short8*)(Bswz + ((size_t)T*8 + q)*512 + (size_t)l*8);
            acc[p] = __builtin_amdgcn_mfma_f32_16x16x32_bf16(a, b, acc[p], 0, 0, 0);
        }
    }
    #pragma unroll
    for (int p = 0; p < 2; ++p){
        int n = (2*w + p)*16 + lm;
        float bs = bias[n];
        #pragma unroll
        for (int r = 0; r < 4; ++r)
            stage[(lq*4 + r)*256 + n] = f2b(acc[p][r] + bs);
    }
    __syncthreads();
    int row = tid >> 5, c8 = tid & 31;
    int4 v = *(const int4*)(stage + row*256 + c8*8);
    *(int4*)(out + (r0 + row)*256 + (size_t)c8*8) = v;
}

// ---- W1P[rows x 64] = A[rows x 256] @ W1swz(4 tiles), f32 out (no bias) ----
__global__ __launch_bounds__(256) void k_gemm64(const ushortT* __restrict__ A,
        const ushortT* __restrict__ Bswz, float* __restrict__ out){
    int tid = threadIdx.x, w = tid >> 6, l = tid & 63, lm = l & 15, lq = l >> 4;
    size_t r0 = (size_t)blockIdx.x * 16;
    const f32x4 fz = {0.f,0.f,0.f,0.f};
    f32x4 acc = fz;
    for (int q = 0; q < 8; ++q){
        short8 a = *(const short8*)(A + (r0 + lm)*256 + q*32 + lq*8);
        short8 b = *(const short8*)(Bswz + ((size_t)w*8 + q)*512 + (size_t)l*8);
        acc = __builtin_amdgcn_mfma_f32_16x16x32_bf16(a, b, acc, 0, 0, 0);
    }
    #pragma unroll
    for (int r = 0; r < 4; ++r)
        out[(r0 + lq*4 + r)*64 + w*16 + lm] = acc[r];
}

// ---- gates pre-act: xg = A@Uall + (Wall_b+Uall_b), written in scan per-lane order ----
__global__ __launch_bounds__(512) void k_gemmgates(const ushortT* __restrict__ A,
        const ushortT* __restrict__ Bswz, const float* __restrict__ bW,
        const float* __restrict__ bU, ushortT* __restrict__ out){
    int tid = threadIdx.x, w = tid >> 6, l = tid & 63, lm = l & 15, lq = l >> 4;
    int g = blockIdx.x / SEQ, t = blockIdx.x % SEQ;
    const f32x4 fz = {0.f,0.f,0.f,0.f};
    f32x4 acc[8] = {fz,fz,fz,fz,fz,fz,fz,fz};
    const ushortT* Arow = A + ((size_t)(g*16 + lm)*SEQ + t)*256;
    for (int q = 0; q < 8; ++q){
        short8 a = *(const short8*)(Arow + q*32 + lq*8);
        #pragma unroll
        for (int gq = 0; gq < 4; ++gq)
        #pragma unroll
        for (int p = 0; p < 2; ++p){
            int T = gq*16 + 2*w + p;
            short8 b = *(const short8*)(Bswz + ((size_t)T*8 + q)*512 + (size_t)l*8);
            acc[gq*2+p] = __builtin_amdgcn_mfma_f32_16x16x32_bf16(a, b, acc[gq*2+p], 0, 0, 0);
        }
    }
    short8 ch[4];
    #pragma unroll
    for (int gq = 0; gq < 4; ++gq)
    #pragma unroll
    for (int p = 0; p < 2; ++p){
        int n = gq*256 + w*32 + p*16 + lm;
        float bs = bW[n] + bU[n];
        #pragma unroll
        for (int r = 0; r < 4; ++r)
            ((ushortT*)&ch[p*2 + (gq>>1)])[(gq&1)*4 + r] = f2b(acc[gq*2+p][r] + bs);
    }
    size_t base = (size_t)(g*SEQ + t)*16384 + (size_t)(w*64 + l)*32;
    #pragma unroll
    for (int ci = 0; ci < 4; ++ci) *(short8*)(out + base + ci*8) = ch[ci];
}

// ---- zero the exchange flags (fresh per launch) ----
__global__ void k_zeroflags(unsigned* __restrict__ f){
    f[blockIdx.x*256 + threadIdx.x] = 0;
}

// ---- persistent TLSTM scan: 32 WGs (2 per batch-group), 512 threads / 8 waves each ----
// ONE barrier per step. Wave w owns cols cw=h*8+w. Weight slots permuted q^=4h so
// slots 0..3 = LOCAL K-half, 4..7 = REMOTE. gq0/1/2 in regs; gq3 + Wd in LDS.
// Remote h/c fragments preloaded into VGPRs one step ahead (after the spin), so the
// MFMA block runs uninterrupted. Flags: per-wave release fetch_add (8/step); spin is
// lane0-poll + shfl broadcast.
#define SL  132
#define HCL (16*SL)
__global__ __launch_bounds__(512, 2) void k_scan(const ushortT* __restrict__ xg,
        const ushortT* __restrict__ tftg, const ushortT* __restrict__ Wswz,
        const ushortT* __restrict__ twswz, const float* __restrict__ wdb_g,
        const float* __restrict__ timeb, ushortT* __restrict__ hs,
        float* __restrict__ maxh, int write_hs,
        ushortT* __restrict__ xbuf, unsigned* __restrict__ flags, unsigned fb8){
    extern __shared__ ushortT smem[];
    // smem: hbL[2] = [0..2*HCL), cbL[2] = [2*HCL..4*HCL), gq3 tiles, Wd tiles
    ushortT* wl3b = smem + 4*HCL;
    ushortT* wlDb = smem + 4*HCL + 32768;
    int tid = threadIdx.x, w = tid >> 6, l = tid & 63, lm = l & 15, lq = l >> 4;
    int blk = blockIdx.x;
    int h = blk >> 4, g = blk & 15;
    int pblk = (1 - h)*16 + g;           // partner block
    int cw = h*8 + w;                    // global 16-col tile index 0..15
    int col = cw*16 + lm;
    int l8 = l*8, h4 = h*4;
    float wdb = wdb_g[col];
    float tb  = timeb[col];
    short8 twf[2];
    #pragma unroll
    for (int q2 = 0; q2 < 2; ++q2)
        twf[q2] = *(const short8*)(twswz + ((size_t)cw*8 + q2)*512 + l8);
    // register weights, slot s holds global q = s ^ h4 (slots 0..3 local, 4..7 remote)
    short8 wg0[8], wg1[8], wg2[8];
    #pragma unroll
    for (int s = 0; s < 8; ++s){
        int q = s ^ h4;
        wg0[s] = *(const short8*)(Wswz + ((size_t)( 0 + cw)*8 + q)*512 + l8);
        wg1[s] = *(const short8*)(Wswz + ((size_t)(16 + cw)*8 + q)*512 + l8);
        wg2[s] = *(const short8*)(Wswz + ((size_t)(32 + cw)*8 + q)*512 + l8);
    }
    float c[4], hm[4];
    #pragma unroll
    for (int i = 0; i < 4; ++i){ c[i] = 0.0f; hm[i] = -2.0f; }
    // zero parity-1 local buffers (read at t=0)
    for (int i = tid; i < HCL; i += 512){ smem[HCL + i] = 0; smem[3*HCL + i] = 0; }
    // preload gq3 + Wd tiles (permuted q slots) into LDS, 64 KB each
    {
        const int4* s3 = (const int4*)(Wswz + (size_t)(48 + h*8)*4096);
        const int4* sD = (const int4*)(Wswz + (size_t)(64 + h*8)*4096);
        int4* d3 = (int4*)wl3b;
        int4* dD = (int4*)wlDb;
        for (int i = tid; i < 4096; i += 512){
            int qc = (i >> 6) & 7, rest = i & ~(7 << 6);
            int j = rest | ((qc ^ h4) << 6);
            d3[j] = s3[i];
            dD[j] = sD[i];
        }
    }
    __syncthreads();

    const ushortT* xg_g  = xg   + (size_t)g*SEQ*16384 + ((size_t)(cw>>1)*64 + l)*32 + (cw&1)*16;
    const ushortT* tft_g = tftg + (size_t)g*SEQ*1024  + (size_t)l8;
    const ushortT* wl3   = wl3b + (size_t)w*4096 + l8;
    const ushortT* wlD   = wlDb + (size_t)w*4096 + l8;
    const f32x4 fz = {0.f,0.f,0.f,0.f};
    const short8 sz = {0,0,0,0,0,0,0,0};
    // remote fragments (partner half), one step ahead; t=0 state is zero
    short8 ra0=sz, ra1=sz, ra2=sz, ra3=sz, rc0=sz, rc1=sz, rc2=sz, rc3=sz;
    short8 xA = *(const short8*)(xg_g);
    short8 xB = *(const short8*)(xg_g + 8);

    for (int t = 0; t < SEQ; ++t){
        int pb = t & 1, ab = 1 - pb;
        const ushortT* hbL = smem + (size_t)ab*HCL;
        const ushortT* cbL = smem + 2*HCL + (size_t)ab*HCL;
        // this-step tft (L2/L3, covered by MFMA phase) + next-step xg (HBM prefetch)
        short8 aT0 = *(const short8*)(tft_g + (size_t)t*1024);
        short8 aT1 = *(const short8*)(tft_g + (size_t)t*1024 + 512);
        size_t tn = (size_t)(t+1 < SEQ ? t+1 : t);
        short8 nxA = *(const short8*)(xg_g + tn*16384);
        short8 nxB = *(const short8*)(xg_g + tn*16384 + 8);

        f32x4 acc[5];
        #pragma unroll
        for (int i = 0; i < 5; ++i) acc[i] = fz;
        // ---- local K-half (slots 0..3) from LDS ----
        #pragma unroll
        for (int s = 0; s < 4; ++s){
            short8 a  = *(const short8*)(hbL + lm*SL + s*32 + lq*8);
            short8 ca = *(const short8*)(cbL + lm*SL + s*32 + lq*8);
            short8 b3 = *(const short8*)(wl3 + s*512);
            short8 bd = *(const short8*)(wlD + s*512);
            acc[0] = __builtin_amdgcn_mfma_f32_16x16x32_bf16(a,  wg0[s], acc[0], 0, 0, 0);
            acc[1] = __builtin_amdgcn_mfma_f32_16x16x32_bf16(a,  wg1[s], acc[1], 0, 0, 0);
            acc[2] = __builtin_amdgcn_mfma_f32_16x16x32_bf16(a,  wg2[s], acc[2], 0, 0, 0);
            acc[3] = __builtin_amdgcn_mfma_f32_16x16x32_bf16(a,  b3,     acc[3], 0, 0, 0);
            acc[4] = __builtin_amdgcn_mfma_f32_16x16x32_bf16(ca, bd,     acc[4], 0, 0, 0);
        }
        f32x4 acc_ts = fz;
        acc_ts = __builtin_amdgcn_mfma_f32_16x16x32_bf16(aT0, twf[0], acc_ts, 0, 0, 0);
        acc_ts = __builtin_amdgcn_mfma_f32_16x16x32_bf16(aT1, twf[1], acc_ts, 0, 0, 0);
        // ---- remote K-half (slots 4..7) from preloaded regs ----
        {
            short8 b3, bd;
            b3 = *(const short8*)(wl3 + 4*512); bd = *(const short8*)(wlD + 4*512);
            acc[0] = __builtin_amdgcn_mfma_f32_16x16x32_bf16(ra0, wg0[4], acc[0], 0, 0, 0);
            acc[1] = __builtin_amdgcn_mfma_f32_16x16x32_bf16(ra0, wg1[4], acc[1], 0, 0, 0);
            acc[2] = __builtin_amdgcn_mfma_f32_16x16x32_bf16(ra0, wg2[4], acc[2], 0, 0, 0);
            acc[3] = __builtin_amdgcn_mfma_f32_16x16x32_bf16(ra0, b3,     acc[3], 0, 0, 0);
            acc[4] = __builtin_amdgcn_mfma_f32_16x16x32_bf16(rc0, bd,     acc[4], 0, 0, 0);
            b3 = *(const short8*)(wl3 + 5*512); bd = *(const short8*)(wlD + 5*512);
            acc[0] = __builtin_amdgcn_mfma_f32_16x16x32_bf16(ra1, wg0[5], acc[0], 0, 0, 0);
            acc[1] = __builtin_amdgcn_mfma_f32_16x16x32_bf16(ra1, wg1[5], acc[1], 0, 0, 0);
            acc[2] = __builtin_amdgcn_mfma_f32_16x16x32_bf16(ra1, wg2[5], acc[2], 0, 0, 0);
            acc[3] = __builtin_amdgcn_mfma_f32_16x16x32_bf16(ra1, b3,     acc[3], 0, 0, 0);
            acc[4] = __builtin_amdgcn_mfma_f32_16x16x32_bf16(rc1, bd,     acc[4], 0, 0, 0);
            b3 = *(const short8*)(wl3 + 6*512); bd = *(const short8*)(wlD + 6*512);
            acc[0] = __builtin_amdgcn_mfma_f32_16x16x32_bf16(ra2, wg0[6], acc[0], 0, 0, 0);
            acc[1] = __builtin_amdgcn_mfma_f32_16x16x32_bf16(ra2, wg1[6], acc[1], 0, 0, 0);
            acc[2] = __builtin_amdgcn_mfma_f32_16x16x32_bf16(ra2, wg2[6], acc[2], 0, 0, 0);
            acc[3] = __builtin_amdgcn_mfma_f32_16x16x32_bf16(ra2, b3,     acc[3], 0, 0, 0);
            acc[4] = __builtin_amdgcn_mfma_f32_16x16x32_bf16(rc2, bd,     acc[4], 0, 0, 0);
            b3 = *(const short8*)(wl3 + 7*512); bd = *(const short8*)(wlD + 7*512);
            acc[0] = __builtin_amdgcn_mfma_f32_16x16x32_bf16(ra3, wg0[7], acc[0], 0, 0, 0);
            acc[1] = __builtin_amdgcn_mfma_f32_16x16x32_bf16(ra3, wg1[7], acc[1], 0, 0, 0);
            acc[2] = __builtin_amdgcn_mfma_f32_16x16x32_bf16(ra3, wg2[7], acc[2], 0, 0, 0);
            acc[3] = __builtin_amdgcn_mfma_f32_16x16x32_bf16(ra3, b3,     acc[3], 0, 0, 0);
            acc[4] = __builtin_amdgcn_mfma_f32_16x16x32_bf16(rc3, bd,     acc[4], 0, 0, 0);
        }

        ushortT* hbw = smem + (size_t)pb*HCL;
        ushortT* cbw = smem + 2*HCL + (size_t)pb*HCL;
        int colL = w*16 + lm;
        #pragma unroll
        for (int r = 0; r < 4; ++r){
            float F   = acc[0][r] + b2f(((const ushortT*)&xA)[r]);
            float I   = acc[1][r] + b2f(((const ushortT*)&xA)[4+r]);
            float O   = acc[2][r] + b2f(((const ushortT*)&xB)[r]);
            float CT  = acc[3][r] + b2f(((const ushortT*)&xB)[4+r]);
            float cwd = acc[4][r] + wdb;
            float ts  = acc_ts[r] + tb;
            float cc  = c[r];
            float cs1 = tanh_fast(cwd);
            float cadj = cc - cs1 + cs1*ts;
            float cn  = sigm(F)*cadj + sigm(I)*sigm(CT);
            float hv  = sigm(O)*tanh_fast(cn);
            c[r]  = cn;
            hm[r] = fmaxf(hm[r], hv);
            hbw[(lq*4 + r)*SL + colL] = f2b(hv);
            cbw[(lq*4 + r)*SL + colL] = f2b(cn);
        }
        __syncthreads();                                   // the ONLY barrier per step
        if (t < SEQ-1){
            // export my h/c slice (16B/thread coalesced, agent-scope)
            int part = tid >> 8, i = tid & 255, row = i >> 4, c16 = i & 15;
            const ushortT* src = (part ? cbw : hbw) + row*SL + c16*8;
            union { int4 v; unsigned long long uu[2]; } u; u.v = *(const int4*)src;
            unsigned long long* dst = (unsigned long long*)(xbuf +
                ((((size_t)blk*2 + pb)*2 + part)*16 + row)*128 + c16*8);
            __hip_atomic_store(dst+0, u.uu[0], __ATOMIC_RELAXED, __HIP_MEMORY_SCOPE_AGENT);
            __hip_atomic_store(dst+1, u.uu[1], __ATOMIC_RELAXED, __HIP_MEMORY_SCOPE_AGENT);
            if (write_hs && !part)
                *(int4*)(hs + ((size_t)(g*16 + row)*SEQ + t)*256 + h*128 + c16*8) = u.v;
            // per-wave release add (drains this wave's stores), then spin for partner
            if (l == 0)
                __hip_atomic_fetch_add(&flags[(size_t)blk*64], 1u,
                                       __ATOMIC_RELEASE, __HIP_MEMORY_SCOPE_AGENT);
            unsigned want = fb8 + 8u*(unsigned)(t+1);
            unsigned v = 0;
            for (int it = 0; it < 20000000; ++it){
                if (l == 0)
                    v = __hip_atomic_load(&flags[(size_t)pblk*64],
                                          __ATOMIC_ACQUIRE, __HIP_MEMORY_SCOPE_AGENT);
                v = __shfl(v, 0, 64);
                if (v >= want) break;
                __builtin_amdgcn_s_sleep(1);
            }
            // preload partner fragments for step t+1 (slot parity pb)
            const ushortT* hsrc = xbuf + ((((size_t)pblk*2 + pb)*2 + 0)*16 + lm)*128 + lq*8;
            const ushortT* csrc = xbuf + ((((size_t)pblk*2 + pb)*2 + 1)*16 + lm)*128 + lq*8;
            ra0 = ld_frag16(hsrc +  0); ra1 = ld_frag16(hsrc + 32);
            ra2 = ld_frag16(hsrc + 64); ra3 = ld_frag16(hsrc + 96);
            rc0 = ld_frag16(csrc +  0); rc1 = ld_frag16(csrc + 32);
            rc2 = ld_frag16(csrc + 64); rc3 = ld_frag16(csrc + 96);
        } else if (write_hs && tid < 256){
            int row = tid >> 4, c16 = tid & 15;
            int4 v = *(const int4*)(hbw + row*SL + c16*8);
            *(int4*)(hs + ((size_t)(g*16 + row)*SEQ + t)*256 + h*128 + c16*8) = v;
        }
        xA = nxA; xB = nxB;
    }
    #pragma unroll
    for (int r = 0; r < 4; ++r)
        maxh[(size_t)(g*16 + lq*4 + r)*256 + col] = hm[r];
}

// ---- snapshot e_k = x[:,0,:] (bf16) ----
__global__ void k_ekcopy(const ushortT* __restrict__ x, ushortT* __restrict__ ek){
    int b = blockIdx.x, l = threadIdx.x;   // 64 threads, 4 ushorts each
    ((int2*)(ek + (size_t)b*256))[l] = ((const int2*)(x + (size_t)b*SEQ*256))[l];
}

// ---- e_k @ w1[0:256] + w1_b (f32 weights) ----
__global__ void k_ekw(const ushortT* __restrict__ ek, const float* __restrict__ w1w,
                      const float* __restrict__ w1b, float* __restrict__ ekw){
    int b = blockIdx.x, l = threadIdx.x;
    float acc = w1b[l];
    const ushortT* e = ek + (size_t)b*256;
    for (int d = 0; d < 256; ++d)
        acc += b2f(e[d]) * w1w[(size_t)d*64 + l];
    ekw[b*64 + l] = acc;
}

// ---- attention + aligned + gen_x, one wave per (b, s'); w1-part precomputed in W1P ----
__global__ __launch_bounds__(512) void k_attn(const ushortT* __restrict__ ekbuf,
        const ushortT* __restrict__ whk, const float* __restrict__ ekw,
        const float* __restrict__ w1p, const float* __restrict__ w2w,
        const float* __restrict__ w2b, const float* __restrict__ nn,
        const float* __restrict__ pn, ushortT* __restrict__ genx){
    int w = threadIdx.x >> 6, l = threadIdx.x & 63;
    int wid = blockIdx.x*8 + w;
    int b = wid / SEQ, sp = wid % SEQ;
    const ushortT* ek = ekbuf + (size_t)b*256;
    const ushortT* wr = whk + ((size_t)b*SEQ + (sp > 0 ? sp-1 : 0))*256;
    size_t orow = ((size_t)b*SEQ + sp)*256;
    float a0, a1;
    if (sp == 0){ a0 = 1.0f; a1 = 0.0f; }
    else {
        float acc = ekw[b*64 + l] + w1p[((size_t)b*SEQ + sp-1)*64 + l];
        float u  = tanh_fast(acc);
        float p0 = u * w2w[l*2 + 0];
        float p1 = u * w2w[l*2 + 1];
        #pragma unroll
        for (int off = 32; off >= 1; off >>= 1){
            p0 += __shfl_xor(p0, off, 64);
            p1 += __shfl_xor(p1, off, 64);
        }
        float v0 = p0 + w2b[0], v1 = p1 + w2b[1];
        a0 = sigm(v0 - v1); a1 = 1.0f - a0;
    }
    #pragma unroll
    for (int i = 0; i < 4; ++i){
        int d = i*64 + l;
        float al = b2f(ek[d])*a0 + b2f(wr[d])*a1;
        float gv = al + nn[orow + d] - pn[orow + d];
        genx[orow + d] = f2b(gv);
    }
}

// ---- heads: out = maxh @ out_w + out_b (all f32) ----
__global__ void k_final(const float* __restrict__ mh1, const float* __restrict__ mh2,
                        const float* __restrict__ ow, const float* __restrict__ ob,
                        float* __restrict__ outp){
    int th = threadIdx.x;
    const float* mh = blockIdx.x ? mh2 : mh1;
    int b = th >> 1, cc = th & 1;
    float acc = ob[cc];
    for (int d = 0; d < 256; ++d)
        acc += mh[b*256 + d] * ow[d*2 + cc];
    outp[blockIdx.x*512 + th] = acc;
}

extern "C" void kernel_launch(void* const* d_in, const int* in_sizes, int n_in,
                              void* d_out, int out_size, void* d_ws, size_t ws_size,
                              hipStream_t stream) {
    const float* input_seqs = (const float*)d_in[0];
    const float* seq_time   = (const float*)d_in[3];
    const float* nn     = (const float*)d_in[6];
    const float* pn     = (const float*)d_in[7];
    const float* emb2_w = (const float*)d_in[9];
    const float* emb2_b = (const float*)d_in[10];
    const float* Wall_w = (const float*)d_in[11];
    const float* Wall_b = (const float*)d_in[12];
    const float* Uall_w = (const float*)d_in[13];
    const float* Uall_b = (const float*)d_in[14];
    const float* Wd_w   = (const float*)d_in[15];
    const float* Wd_b   = (const float*)d_in[16];
    const float* time_w = (const float*)d_in[17];
    const float* time_b = (const float*)d_in[18];
    const float* sel_w  = (const float*)d_in[19];
    const float* sel_b  = (const float*)d_in[20];
    const float* whk_w  = (const float*)d_in[21];
    const float* whk_b  = (const float*)d_in[22];
    const float* w1_w   = (const float*)d_in[23];
    const float* w1_b   = (const float*)d_in[24];
    const float* w2_w   = (const float*)d_in[25];
    const float* w2_b   = (const float*)d_in[26];
    const float* out_w  = (const float*)d_in[27];
    const float* out_b  = (const float*)d_in[28];

    const size_t NSZ = (size_t)in_sizes[6];   // B*SEQ*D noise element count

    // allow >64KB dynamic LDS for k_scan (160 KB/CU on gfx950)
    static bool attr_done = false;
    if (!attr_done){
        hipFuncSetAttribute((const void*)k_scan,
                            hipFuncAttributeMaxDynamicSharedMemorySize, 160*1024);
        attr_done = true;
    }
    const size_t SCAN_LDS = (size_t)(4*HCL + 2*32768) * sizeof(ushortT);  // 147,968 B

    char* wsb = (char*)d_ws;
    size_t off = 0;
    auto alloc = [&](size_t bytes){ void* p = wsb + off; off += (bytes + 255) & ~(size_t)255; return p; };
    ushortT* Wswz  = (ushortT*)alloc(80u*8*512*2);     // Wall tiles 0..63, Wd tiles 64..79
    ushortT* Uswz  = (ushortT*)alloc(64u*8*512*2);
    ushortT* Eswz  = (ushortT*)alloc(16u*8*512*2);
    ushortT* Hswz  = (ushortT*)alloc(16u*8*512*2);
    ushortT* TWswz = (ushortT*)alloc(16u*8*512*2);     // time_w (only q=0,1 slots used)
    ushortT* W1swz = (ushortT*)alloc(4u*8*512*2);      // w1_w rows 256..511 (4 tiles)
    ushortT* TFT   = (ushortT*)alloc((size_t)16*SEQ*1024*2);   // 6.6 MB
    ushortT* X     = (ushortT*)alloc((size_t)NB*SEQ*256*2);    // 26.2 MB (reused as GENX)
    ushortT* XG    = (ushortT*)alloc((size_t)16*SEQ*16384*2);  // 100 MB
    ushortT* HS    = (ushortT*)alloc((size_t)NB*SEQ*256*2);    // 26.2 MB (also input bf16 staging)
    ushortT* EK    = (ushortT*)alloc((size_t)NB*256*2);
    float*  MAXH1  = (float*)alloc((size_t)NB*256*4);
    float*  MAXH2  = (float*)alloc((size_t)NB*256*4);
    float*  EKW    = (float*)alloc((size_t)NB*64*4);
    float*  W1P    = (float*)alloc((size_t)NB*SEQ*64*4);       // 13.1 MB
    ushortT* XBUF  = (ushortT*)alloc((size_t)32*2*2*16*128*2); // 512 KB pair-exchange
    unsigned* FLAGS= (unsigned*)alloc((size_t)32*64*4);        // 8 KB, 256B-strided flags

    float* outp = (float*)d_out;
    // outputs 2,3 are pass-throughs (predicted_noise, normal_noise), f32
    hipMemcpyAsync(outp + 1024,       pn, NSZ*4, hipMemcpyDeviceToDevice, stream);
    hipMemcpyAsync(outp + 1024 + NSZ, nn, NSZ*4, hipMemcpyDeviceToDevice, stream);

    k_zeroflags<<<8, 256, 0, stream>>>(FLAGS);
    k_swizzle<<<dim3(64,8), 64, 0, stream>>>(Wall_w, 1024, Wswz, 0);
    k_swizzle<<<dim3(16,8), 64, 0, stream>>>(Wd_w,    256, Wswz, 64);
    k_swizzle<<<dim3(64,8), 64, 0, stream>>>(Uall_w, 1024, Uswz, 0);
    k_swizzle<<<dim3(16,8), 64, 0, stream>>>(emb2_w,  256, Eswz, 0);
    k_swizzle<<<dim3(16,8), 64, 0, stream>>>(whk_w,   256, Hswz, 0);
    k_swizzle<<<dim3(16,2), 64, 0, stream>>>(time_w,  256, TWswz, 0);  // K=64 → q<2
    k_swizzle<<<dim3(4,8),  64, 0, stream>>>(w1_w + 256*64, 64, W1swz, 0);

    k_tft<<<3200, 64, 0, stream>>>(seq_time, sel_w, sel_b, TFT);
    k_cvt<<<12800, 256, 0, stream>>>(input_seqs, HS);          // f32 input → bf16 (staged in HS)
    k_gemm256<<<3200, 512, 0, stream>>>(HS, Eswz, emb2_b, X);
    k_ekcopy<<<256, 64, 0, stream>>>(X, EK);
    k_ekw<<<256, 64, 0, stream>>>(EK, w1_w, w1_b, EKW);
    k_gemmgates<<<3200, 512, 0, stream>>>(X, Uswz, Wall_b, Uall_b, XG);
    k_scan<<<32, 512, SCAN_LDS, stream>>>(XG, TFT, Wswz, TWswz, Wd_b, time_b, HS, MAXH1, 1,
                                          XBUF, FLAGS, 0u);
    k_gemm256<<<3200, 512, 0, stream>>>(HS, Hswz, whk_b, HS);   // whk in-place (block-local rows)
    k_gemm64<<<3200, 256, 0, stream>>>(HS, W1swz, W1P);         // whk @ w1[256:512] (f32)
    k_attn<<<6400, 512, 0, stream>>>(EK, HS, EKW, W1P, w2_w, w2_b, nn, pn, X);  // genx → X region
    k_gemmgates<<<3200, 512, 0, stream>>>(X, Uswz, Wall_b, Uall_b, XG);
    k_scan<<<32, 512, SCAN_LDS, stream>>>(XG, TFT, Wswz, TWswz, Wd_b, time_b, HS, MAXH2, 0,
                                          XBUF, FLAGS, 8u*(SEQ-1));
    k_final<<<2, 512, 0, stream>>>(MAXH1, MAXH2, out_w, out_b, outp);
}

// Round 8
// 4306.130 us; speedup vs baseline: 1.0851x; 1.0851x over previous
//
#include <hip/hip_runtime.h>
#include <hip/hip_bf16.h>
#include <cstdint>

typedef __attribute__((ext_vector_type(8))) short short8;
typedef __attribute__((ext_vector_type(4))) float f32x4;
typedef unsigned short ushortT;

#define SEQ 200
#define NB  256

__device__ __forceinline__ float b2f(ushortT u){
    union { unsigned u; float f; } v; v.u = ((unsigned)u) << 16; return v.f;
}
__device__ __forceinline__ ushortT f2b(float f){
    union { float f; unsigned u; } v; v.f = f;
    unsigned r = v.u + 0x7FFFu + ((v.u >> 16) & 1u);
    return (ushortT)(r >> 16);
}
// fast reciprocal: ~1 ulp, far below bf16 rounding; avoids the full div sequence
__device__ __forceinline__ float frcp(float x){
    float r; asm("v_rcp_f32 %0, %1" : "=v"(r) : "v"(x)); return r;
}
__device__ __forceinline__ float sigm(float x){ return frcp(1.0f + __expf(-x)); }
__device__ __forceinline__ float tanh_fast(float x){
    float ax = fabsf(x);
    float t = __expf(-2.0f * ax);
    float r = (1.0f - t) * frcp(1.0f + t);
    return copysignf(r, x);
}
// load one remote q-slot (8 packed u32 {h,c}) and unpack to h/c bf16 fragments
__device__ __forceinline__ void load_slot(const unsigned* p, short8& hf, short8& cf){
    const unsigned long long* q = (const unsigned long long*)p;
    unsigned long long d0 = __hip_atomic_load(q+0, __ATOMIC_RELAXED, __HIP_MEMORY_SCOPE_AGENT);
    unsigned long long d1 = __hip_atomic_load(q+1, __ATOMIC_RELAXED, __HIP_MEMORY_SCOPE_AGENT);
    unsigned long long d2 = __hip_atomic_load(q+2, __ATOMIC_RELAXED, __HIP_MEMORY_SCOPE_AGENT);
    unsigned long long d3 = __hip_atomic_load(q+3, __ATOMIC_RELAXED, __HIP_MEMORY_SCOPE_AGENT);
    unsigned x0=(unsigned)d0, x1=(unsigned)(d0>>32), x2=(unsigned)d1, x3=(unsigned)(d1>>32);
    unsigned x4=(unsigned)d2, x5=(unsigned)(d2>>32), x6=(unsigned)d3, x7=(unsigned)(d3>>32);
    union { short8 v; unsigned u[4]; } H, C;
    H.u[0]=__builtin_amdgcn_perm(x1,x0,0x05040100u); C.u[0]=__builtin_amdgcn_perm(x1,x0,0x07060302u);
    H.u[1]=__builtin_amdgcn_perm(x3,x2,0x05040100u); C.u[1]=__builtin_amdgcn_perm(x3,x2,0x07060302u);
    H.u[2]=__builtin_amdgcn_perm(x5,x4,0x05040100u); C.u[2]=__builtin_amdgcn_perm(x5,x4,0x07060302u);
    H.u[3]=__builtin_amdgcn_perm(x7,x6,0x05040100u); C.u[3]=__builtin_amdgcn_perm(x7,x6,0x07060302u);
    hf = H.v; cf = C.v;
}

// ---- f32 -> bf16 bulk convert (n multiple of 1024) ----
__global__ void k_cvt(const float* __restrict__ in, ushortT* __restrict__ out){
    size_t i = ((size_t)blockIdx.x*256 + threadIdx.x)*4;
    float4 v = *(const float4*)(in + i);
    ushortT o[4] = { f2b(v.x), f2b(v.y), f2b(v.z), f2b(v.w) };
    *(int2*)(out + i) = *(int2*)o;
}

// ---- swizzle a (K x ncols) f32 row-major matrix into bf16 MFMA B-fragment tiles ----
// tile T (16 cols), kstep q (32 k): lane l holds B[k = q*32+(l>>4)*8+j][n = T*16+(l&15)], j=0..7
__global__ void k_swizzle(const float* __restrict__ src, int ncols,
                          ushortT* __restrict__ dst, int tile0){
    int Tl = blockIdx.x, q = blockIdx.y, l = threadIdx.x;
    int n  = Tl*16 + (l & 15);
    int kb = q*32 + (l >> 4)*8;
    short8 v;
    #pragma unroll
    for (int j = 0; j < 8; ++j) ((ushortT*)&v)[j] = f2b(src[(size_t)(kb + j)*ncols + n]);
    *(short8*)(dst + ((size_t)(tile0 + Tl)*8 + q)*512 + (size_t)l*8) = v;
}

// ---- tft = 1 - tanh((t/180*selw+selb)^2), stored as scan A-fragments (bf16) ----
__global__ void k_tft(const float* __restrict__ sts, const float* __restrict__ selw,
                      const float* __restrict__ selb, ushortT* __restrict__ tft){
    int l = threadIdx.x, g = blockIdx.x / SEQ, t = blockIdx.x % SEQ;
    int lm = l & 15, lq = l >> 4;
    float tv = sts[(size_t)(g*16 + lm)*SEQ + t] * (1.0f/180.0f);
    size_t base = (size_t)(g*SEQ + t)*1024 + (size_t)l*8;
    #pragma unroll
    for (int q = 0; q < 2; ++q){
        short8 v;
        #pragma unroll
        for (int j = 0; j < 8; ++j){
            int u = q*32 + lq*8 + j;
            float a = tv * selw[u] + selb[u];
            ((ushortT*)&v)[j] = f2b(1.0f - tanh_fast(a*a));
        }
        *(short8*)(tft + base + (size_t)q*512) = v;
    }
}

// ---- generic C[rows x 256] = A[rows x 256] @ Bswz(16 tiles) + bias(f32), bf16 out ----
__global__ __launch_bounds__(512) void k_gemm256(const ushortT* A,
        const ushortT* __restrict__ Bswz, const float* __restrict__ bias, ushortT* out){
    __shared__ ushortT stage[16*256];
    int tid = threadIdx.x, w = tid >> 6, l = tid & 63, lm = l & 15, lq = l >> 4;
    size_t r0 = (size_t)blockIdx.x * 16;
    const f32x4 fz = {0.f,0.f,0.f,0.f};
    f32x4 acc[2] = {fz, fz};
    for (int q = 0; q < 8; ++q){
        short8 a = *(const short8*)(A + (r0 + lm)*256 + q*32 + lq*8);
        #pragma unroll
        for (int p = 0; p < 2; ++p){
            int T = 2*w + p;
            short8 b = *(const short8*)(Bswz + ((size_t)T*8 + q)*512 + (size_t)l*8);
            acc[p] = __builtin_amdgcn_mfma_f32_16x16x32_bf16(a, b, acc[p], 0, 0, 0);
        }
    }
    #pragma unroll
    for (int p = 0; p < 2; ++p){
        int n = (2*w + p)*16 + lm;
        float bs = bias[n];
        #pragma unroll
        for (int r = 0; r < 4; ++r)
            stage[(lq*4 + r)*256 + n] = f2b(acc[p][r] + bs);
    }
    __syncthreads();
    int row = tid >> 5, c8 = tid & 31;
    int4 v = *(const int4*)(stage + row*256 + c8*8);
    *(int4*)(out + (r0 + row)*256 + (size_t)c8*8) = v;
}

// ---- W1P[rows x 64] = A[rows x 256] @ W1swz(4 tiles), f32 out (no bias) ----
__global__ __launch_bounds__(256) void k_gemm64(const ushortT* __restrict__ A,
        const ushortT* __restrict__ Bswz, float* __restrict__ out){
    int tid = threadIdx.x, w = tid >> 6, l = tid & 63, lm = l & 15, lq = l >> 4;
    size_t r0 = (size_t)blockIdx.x * 16;
    const f32x4 fz = {0.f,0.f,0.f,0.f};
    f32x4 acc = fz;
    for (int q = 0; q < 8; ++q){
        short8 a = *(const short8*)(A + (r0 + lm)*256 + q*32 + lq*8);
        short8 b = *(const short8*)(Bswz + ((size_t)w*8 + q)*512 + (size_t)l*8);
        acc = __builtin_amdgcn_mfma_f32_16x16x32_bf16(a, b, acc, 0, 0, 0);
    }
    #pragma unroll
    for (int r = 0; r < 4; ++r)
        out[(r0 + lq*4 + r)*64 + w*16 + lm] = acc[r];
}

// ---- gates pre-act: xg = A@Uall + (Wall_b+Uall_b), written in scan per-lane order ----
__global__ __launch_bounds__(512) void k_gemmgates(const ushortT* __restrict__ A,
        const ushortT* __restrict__ Bswz, const float* __restrict__ bW,
        const float* __restrict__ bU, ushortT* __restrict__ out){
    int tid = threadIdx.x, w = tid >> 6, l = tid & 63, lm = l & 15, lq = l >> 4;
    int g = blockIdx.x / SEQ, t = blockIdx.x % SEQ;
    const f32x4 fz = {0.f,0.f,0.f,0.f};
    f32x4 acc[8] = {fz,fz,fz,fz,fz,fz,fz,fz};
    const ushortT* Arow = A + ((size_t)(g*16 + lm)*SEQ + t)*256;
    for (int q = 0; q < 8; ++q){
        short8 a = *(const short8*)(Arow + q*32 + lq*8);
        #pragma unroll
        for (int gq = 0; gq < 4; ++gq)
        #pragma unroll
        for (int p = 0; p < 2; ++p){
            int T = gq*16 + 2*w + p;
            short8 b = *(const short8*)(Bswz + ((size_t)T*8 + q)*512 + (size_t)l*8);
            acc[gq*2+p] = __builtin_amdgcn_mfma_f32_16x16x32_bf16(a, b, acc[gq*2+p], 0, 0, 0);
        }
    }
    short8 ch[4];
    #pragma unroll
    for (int gq = 0; gq < 4; ++gq)
    #pragma unroll
    for (int p = 0; p < 2; ++p){
        int n = gq*256 + w*32 + p*16 + lm;
        float bs = bW[n] + bU[n];
        #pragma unroll
        for (int r = 0; r < 4; ++r)
            ((ushortT*)&ch[p*2 + (gq>>1)])[(gq&1)*4 + r] = f2b(acc[gq*2+p][r] + bs);
    }
    size_t base = (size_t)(g*SEQ + t)*16384 + (size_t)(w*64 + l)*32;
    #pragma unroll
    for (int ci = 0; ci < 4; ++ci) *(short8*)(out + base + ci*8) = ch[ci];
}

// ---- zero the exchange flags (fresh per launch) ----
__global__ void k_zeroflags(unsigned* __restrict__ f){
    f[blockIdx.x*256 + threadIdx.x] = 0;
}

// ---- persistent TLSTM scan: 32 WGs (2 per batch-group), 512 threads / 8 waves each ----
// Wave-autonomous exchange: slot-permuted weights (0..3 local LDS-half, 4..7 remote),
// remote h/c fragments in VGPRs loaded directly from partner's xbuf (u32 {h,c} packed).
// Per-wave release-STORE flags (64B-strided, no RMW), 8-lane relaxed poll spin,
// ONE __syncthreads per step. Export/hs written straight from elementwise registers.
#define SL  132
#define HCL (16*SL)
__global__ __launch_bounds__(512, 2) void k_scan(const ushortT* __restrict__ xg,
        const ushortT* __restrict__ tftg, const ushortT* __restrict__ Wswz,
        const ushortT* __restrict__ twswz, const float* __restrict__ wdb_g,
        const float* __restrict__ timeb, ushortT* __restrict__ hs,
        float* __restrict__ maxh, int write_hs,
        unsigned* __restrict__ xbuf, unsigned* __restrict__ flags, unsigned fb){
    extern __shared__ ushortT smem[];
    // smem: hbL[2] = [0..2*HCL), cbL[2] = [2*HCL..4*HCL), gq3 tiles, Wd tiles
    ushortT* wl3b = smem + 4*HCL;
    ushortT* wlDb = smem + 4*HCL + 32768;
    int tid = threadIdx.x, w = tid >> 6, l = tid & 63, lm = l & 15, lq = l >> 4;
    int blk = blockIdx.x;
    int h = blk >> 4, g = blk & 15;
    int pblk = (1 - h)*16 + g;           // partner block
    int cw = h*8 + w;                    // global 16-col tile index 0..15
    int col = cw*16 + lm;
    int l8 = l*8, h4 = h*4;
    float wdb = wdb_g[col];
    float tb  = timeb[col];
    short8 twf[2];
    #pragma unroll
    for (int q2 = 0; q2 < 2; ++q2)
        twf[q2] = *(const short8*)(twswz + ((size_t)cw*8 + q2)*512 + l8);
    // register weights, slot s holds global q = s ^ h4 (slots 0..3 local, 4..7 remote)
    short8 wg0[8], wg1[8], wg2[8];
    #pragma unroll
    for (int s = 0; s < 8; ++s){
        int q = s ^ h4;
        wg0[s] = *(const short8*)(Wswz + ((size_t)( 0 + cw)*8 + q)*512 + l8);
        wg1[s] = *(const short8*)(Wswz + ((size_t)(16 + cw)*8 + q)*512 + l8);
        wg2[s] = *(const short8*)(Wswz + ((size_t)(32 + cw)*8 + q)*512 + l8);
    }
    float c[4], hm[4];
    #pragma unroll
    for (int i = 0; i < 4; ++i){ c[i] = 0.0f; hm[i] = -2.0f; }
    // zero parity-1 local buffers (read at t=0)
    for (int i = tid; i < HCL; i += 512){ smem[HCL + i] = 0; smem[3*HCL + i] = 0; }
    // preload gq3 + Wd tiles (permuted q slots) into LDS, 64 KB each
    {
        const int4* s3 = (const int4*)(Wswz + (size_t)(48 + h*8)*4096);
        const int4* sD = (const int4*)(Wswz + (size_t)(64 + h*8)*4096);
        int4* d3 = (int4*)wl3b;
        int4* dD = (int4*)wlDb;
        for (int i = tid; i < 4096; i += 512){
            int qc = (i >> 6) & 7, rest = i & ~(7 << 6);
            int j = rest | ((qc ^ h4) << 6);
            d3[j] = s3[i];
            dD[j] = sD[i];
        }
    }
    __syncthreads();

    const ushortT* xg_g  = xg   + (size_t)g*SEQ*16384 + ((size_t)(cw>>1)*64 + l)*32 + (cw&1)*16;
    const ushortT* tft_g = tftg + (size_t)g*SEQ*1024  + (size_t)l8;
    const ushortT* wl3   = wl3b + (size_t)w*4096 + l8;
    const ushortT* wlD   = wlDb + (size_t)w*4096 + l8;
    const f32x4 fz = {0.f,0.f,0.f,0.f};
    const short8 sz = {0,0,0,0,0,0,0,0};
    // remote fragments (partner half), loaded one step ahead; t=0 state is zero
    short8 ra0=sz, ra1=sz, ra2=sz, ra3=sz, rc0=sz, rc1=sz, rc2=sz, rc3=sz;

    for (int t = 0; t < SEQ; ++t){
        int pb = t & 1, ab = 1 - pb;
        const ushortT* hbL = smem + (size_t)ab*HCL;
        const ushortT* cbL = smem + 2*HCL + (size_t)ab*HCL;
        short8 xA  = *(const short8*)(xg_g + (size_t)t*16384);
        short8 xB  = *(const short8*)(xg_g + (size_t)t*16384 + 8);
        short8 aT0 = *(const short8*)(tft_g + (size_t)t*1024);
        short8 aT1 = *(const short8*)(tft_g + (size_t)t*1024 + 512);

        f32x4 acc[5];
        #pragma unroll
        for (int i = 0; i < 5; ++i) acc[i] = fz;
        // ---- local K-half (slots 0..3) from LDS ----
        #pragma unroll
        for (int s = 0; s < 4; ++s){
            short8 a  = *(const short8*)(hbL + lm*SL + s*32 + lq*8);
            short8 ca = *(const short8*)(cbL + lm*SL + s*32 + lq*8);
            short8 b3 = *(const short8*)(wl3 + s*512);
            short8 bd = *(const short8*)(wlD + s*512);
            acc[0] = __builtin_amdgcn_mfma_f32_16x16x32_bf16(a,  wg0[s], acc[0], 0, 0, 0);
            acc[1] = __builtin_amdgcn_mfma_f32_16x16x32_bf16(a,  wg1[s], acc[1], 0, 0, 0);
            acc[2] = __builtin_amdgcn_mfma_f32_16x16x32_bf16(a,  wg2[s], acc[2], 0, 0, 0);
            acc[3] = __builtin_amdgcn_mfma_f32_16x16x32_bf16(a,  b3,     acc[3], 0, 0, 0);
            acc[4] = __builtin_amdgcn_mfma_f32_16x16x32_bf16(ca, bd,     acc[4], 0, 0, 0);
        }
        f32x4 acc_ts = fz;
        acc_ts = __builtin_amdgcn_mfma_f32_16x16x32_bf16(aT0, twf[0], acc_ts, 0, 0, 0);
        acc_ts = __builtin_amdgcn_mfma_f32_16x16x32_bf16(aT1, twf[1], acc_ts, 0, 0, 0);
        // ---- remote K-half (slots 4..7) from preloaded regs ----
        {
            short8 b3, bd;
            b3 = *(const short8*)(wl3 + 4*512); bd = *(const short8*)(wlD + 4*512);
            acc[0] = __builtin_amdgcn_mfma_f32_16x16x32_bf16(ra0, wg0[4], acc[0], 0, 0, 0);
            acc[1] = __builtin_amdgcn_mfma_f32_16x16x32_bf16(ra0, wg1[4], acc[1], 0, 0, 0);
            acc[2] = __builtin_amdgcn_mfma_f32_16x16x32_bf16(ra0, wg2[4], acc[2], 0, 0, 0);
            acc[3] = __builtin_amdgcn_mfma_f32_16x16x32_bf16(ra0, b3,     acc[3], 0, 0, 0);
            acc[4] = __builtin_amdgcn_mfma_f32_16x16x32_bf16(rc0, bd,     acc[4], 0, 0, 0);
            b3 = *(const short8*)(wl3 + 5*512); bd = *(const short8*)(wlD + 5*512);
            acc[0] = __builtin_amdgcn_mfma_f32_16x16x32_bf16(ra1, wg0[5], acc[0], 0, 0, 0);
            acc[1] = __builtin_amdgcn_mfma_f32_16x16x32_bf16(ra1, wg1[5], acc[1], 0, 0, 0);
            acc[2] = __builtin_amdgcn_mfma_f32_16x16x32_bf16(ra1, wg2[5], acc[2], 0, 0, 0);
            acc[3] = __builtin_amdgcn_mfma_f32_16x16x32_bf16(ra1, b3,     acc[3], 0, 0, 0);
            acc[4] = __builtin_amdgcn_mfma_f32_16x16x32_bf16(rc1, bd,     acc[4], 0, 0, 0);
            b3 = *(const short8*)(wl3 + 6*512); bd = *(const short8*)(wlD + 6*512);
            acc[0] = __builtin_amdgcn_mfma_f32_16x16x32_bf16(ra2, wg0[6], acc[0], 0, 0, 0);
            acc[1] = __builtin_amdgcn_mfma_f32_16x16x32_bf16(ra2, wg1[6], acc[1], 0, 0, 0);
            acc[2] = __builtin_amdgcn_mfma_f32_16x16x32_bf16(ra2, wg2[6], acc[2], 0, 0, 0);
            acc[3] = __builtin_amdgcn_mfma_f32_16x16x32_bf16(ra2, b3,     acc[3], 0, 0, 0);
            acc[4] = __builtin_amdgcn_mfma_f32_16x16x32_bf16(rc2, bd,     acc[4], 0, 0, 0);
            b3 = *(const short8*)(wl3 + 7*512); bd = *(const short8*)(wlD + 7*512);
            acc[0] = __builtin_amdgcn_mfma_f32_16x16x32_bf16(ra3, wg0[7], acc[0], 0, 0, 0);
            acc[1] = __builtin_amdgcn_mfma_f32_16x16x32_bf16(ra3, wg1[7], acc[1], 0, 0, 0);
            acc[2] = __builtin_amdgcn_mfma_f32_16x16x32_bf16(ra3, wg2[7], acc[2], 0, 0, 0);
            acc[3] = __builtin_amdgcn_mfma_f32_16x16x32_bf16(ra3, b3,     acc[3], 0, 0, 0);
            acc[4] = __builtin_amdgcn_mfma_f32_16x16x32_bf16(rc3, bd,     acc[4], 0, 0, 0);
        }

        ushortT* hbw = smem + (size_t)pb*HCL;
        ushortT* cbw = smem + 2*HCL + (size_t)pb*HCL;
        int colL = w*16 + lm;
        unsigned hc[4];
        #pragma unroll
        for (int r = 0; r < 4; ++r){
            float F   = acc[0][r] + b2f(((const ushortT*)&xA)[r]);
            float I   = acc[1][r] + b2f(((const ushortT*)&xA)[4+r]);
            float O   = acc[2][r] + b2f(((const ushortT*)&xB)[r]);
            float CT  = acc[3][r] + b2f(((const ushortT*)&xB)[4+r]);
            float cwd = acc[4][r] + wdb;
            float ts  = acc_ts[r] + tb;
            float cc  = c[r];
            float cs1 = tanh_fast(cwd);
            float cadj = cc - cs1 + cs1*ts;
            float cn  = sigm(F)*cadj + sigm(I)*sigm(CT);
            float hv  = sigm(O)*tanh_fast(cn);
            c[r]  = cn;
            hm[r] = fmaxf(hm[r], hv);
            ushortT hbf = f2b(hv), cbf = f2b(cn);
            hbw[(lq*4 + r)*SL + colL] = hbf;
            cbw[(lq*4 + r)*SL + colL] = cbf;
            hc[r] = (unsigned)hbf | ((unsigned)cbf << 16);
        }
        if (t < SEQ-1){
            // export my h/c slice straight from regs: u32 {h,c}, 64B-chunk coalesced
            unsigned* xd = xbuf + ((size_t)(blk*2 + pb)*16)*128 + (size_t)w*16 + lm;
            #pragma unroll
            for (int r = 0; r < 4; ++r)
                __hip_atomic_store(xd + (size_t)(lq*4 + r)*128, hc[r],
                                   __ATOMIC_RELAXED, __HIP_MEMORY_SCOPE_AGENT);
            unsigned want = fb + (unsigned)t + 1u;
            if (l == 0)   // release drains this wave's export stores
                __hip_atomic_store(&flags[(size_t)(blk*8 + w)*16], want,
                                   __ATOMIC_RELEASE, __HIP_MEMORY_SCOPE_AGENT);
            if (write_hs){
                #pragma unroll
                for (int r = 0; r < 4; ++r)
                    hs[((size_t)(g*16 + lq*4 + r)*SEQ + t)*256 + col] = (ushortT)hc[r];
            }
            // spin: lanes 0..7 poll partner's 8 wave-flags, relaxed (L1-bypass)
            {
                const unsigned* pf = flags + (size_t)(pblk*8 + l)*16;
                for (int it = 0; it < 20000000; ++it){
                    unsigned fv = (l < 8)
                        ? __hip_atomic_load(pf, __ATOMIC_RELAXED, __HIP_MEMORY_SCOPE_AGENT)
                        : want;
                    if (__all((int)(fv >= want))) break;
                    __builtin_amdgcn_s_sleep(1);
                }
            }
            // load partner fragments for step t+1 (slot parity pb)
            const unsigned* rb = xbuf + ((size_t)(pblk*2 + pb)*16 + lm)*128 + lq*8;
            load_slot(rb +  0, ra0, rc0);
            load_slot(rb + 32, ra1, rc1);
            load_slot(rb + 64, ra2, rc2);
            load_slot(rb + 96, ra3, rc3);
            __syncthreads();             // the ONLY barrier per step
        } else if (write_hs){
            #pragma unroll
            for (int r = 0; r < 4; ++r)
                hs[((size_t)(g*16 + lq*4 + r)*SEQ + t)*256 + col] = (ushortT)hc[r];
        }
    }
    #pragma unroll
    for (int r = 0; r < 4; ++r)
        maxh[(size_t)(g*16 + lq*4 + r)*256 + col] = hm[r];
}

// ---- snapshot e_k = x[:,0,:] (bf16) ----
__global__ void k_ekcopy(const ushortT* __restrict__ x, ushortT* __restrict__ ek){
    int b = blockIdx.x, l = threadIdx.x;   // 64 threads, 4 ushorts each
    ((int2*)(ek + (size_t)b*256))[l] = ((const int2*)(x + (size_t)b*SEQ*256))[l];
}

// ---- e_k @ w1[0:256] + w1_b (f32 weights) ----
__global__ void k_ekw(const ushortT* __restrict__ ek, const float* __restrict__ w1w,
                      const float* __restrict__ w1b, float* __restrict__ ekw){
    int b = blockIdx.x, l = threadIdx.x;
    float acc = w1b[l];
    const ushortT* e = ek + (size_t)b*256;
    for (int d = 0; d < 256; ++d)
        acc += b2f(e[d]) * w1w[(size_t)d*64 + l];
    ekw[b*64 + l] = acc;
}

// ---- attention + aligned + gen_x, one wave per (b, s'); w1-part precomputed in W1P ----
__global__ __launch_bounds__(512) void k_attn(const ushortT* __restrict__ ekbuf,
        const ushortT* __restrict__ whk, const float* __restrict__ ekw,
        const float* __restrict__ w1p, const float* __restrict__ w2w,
        const float* __restrict__ w2b, const float* __restrict__ nn,
        const float* __restrict__ pn, ushortT* __restrict__ genx){
    int w = threadIdx.x >> 6, l = threadIdx.x & 63;
    int wid = blockIdx.x*8 + w;
    int b = wid / SEQ, sp = wid % SEQ;
    const ushortT* ek = ekbuf + (size_t)b*256;
    const ushortT* wr = whk + ((size_t)b*SEQ + (sp > 0 ? sp-1 : 0))*256;
    size_t orow = ((size_t)b*SEQ + sp)*256;
    float a0, a1;
    if (sp == 0){ a0 = 1.0f; a1 = 0.0f; }
    else {
        float acc = ekw[b*64 + l] + w1p[((size_t)b*SEQ + sp-1)*64 + l];
        float u  = tanh_fast(acc);
        float p0 = u * w2w[l*2 + 0];
        float p1 = u * w2w[l*2 + 1];
        #pragma unroll
        for (int off = 32; off >= 1; off >>= 1){
            p0 += __shfl_xor(p0, off, 64);
            p1 += __shfl_xor(p1, off, 64);
        }
        float v0 = p0 + w2b[0], v1 = p1 + w2b[1];
        a0 = sigm(v0 - v1); a1 = 1.0f - a0;
    }
    #pragma unroll
    for (int i = 0; i < 4; ++i){
        int d = i*64 + l;
        float al = b2f(ek[d])*a0 + b2f(wr[d])*a1;
        float gv = al + nn[orow + d] - pn[orow + d];
        genx[orow + d] = f2b(gv);
    }
}

// ---- heads: out = maxh @ out_w + out_b (all f32) ----
__global__ void k_final(const float* __restrict__ mh1, const float* __restrict__ mh2,
                        const float* __restrict__ ow, const float* __restrict__ ob,
                        float* __restrict__ outp){
    int th = threadIdx.x;
    const float* mh = blockIdx.x ? mh2 : mh1;
    int b = th >> 1, cc = th & 1;
    float acc = ob[cc];
    for (int d = 0; d < 256; ++d)
        acc += mh[b*256 + d] * ow[d*2 + cc];
    outp[blockIdx.x*512 + th] = acc;
}

extern "C" void kernel_launch(void* const* d_in, const int* in_sizes, int n_in,
                              void* d_out, int out_size, void* d_ws, size_t ws_size,
                              hipStream_t stream) {
    const float* input_seqs = (const float*)d_in[0];
    const float* seq_time   = (const float*)d_in[3];
    const float* nn     = (const float*)d_in[6];
    const float* pn     = (const float*)d_in[7];
    const float* emb2_w = (const float*)d_in[9];
    const float* emb2_b = (const float*)d_in[10];
    const float* Wall_w = (const float*)d_in[11];
    const float* Wall_b = (const float*)d_in[12];
    const float* Uall_w = (const float*)d_in[13];
    const float* Uall_b = (const float*)d_in[14];
    const float* Wd_w   = (const float*)d_in[15];
    const float* Wd_b   = (const float*)d_in[16];
    const float* time_w = (const float*)d_in[17];
    const float* time_b = (const float*)d_in[18];
    const float* sel_w  = (const float*)d_in[19];
    const float* sel_b  = (const float*)d_in[20];
    const float* whk_w  = (const float*)d_in[21];
    const float* whk_b  = (const float*)d_in[22];
    const float* w1_w   = (const float*)d_in[23];
    const float* w1_b   = (const float*)d_in[24];
    const float* w2_w   = (const float*)d_in[25];
    const float* w2_b   = (const float*)d_in[26];
    const float* out_w  = (const float*)d_in[27];
    const float* out_b  = (const float*)d_in[28];

    const size_t NSZ = (size_t)in_sizes[6];   // B*SEQ*D noise element count

    // allow >64KB dynamic LDS for k_scan (160 KB/CU on gfx950)
    static bool attr_done = false;
    if (!attr_done){
        hipFuncSetAttribute((const void*)k_scan,
                            hipFuncAttributeMaxDynamicSharedMemorySize, 160*1024);
        attr_done = true;
    }
    const size_t SCAN_LDS = (size_t)(4*HCL + 2*32768) * sizeof(ushortT);  // 147,968 B

    char* wsb = (char*)d_ws;
    size_t off = 0;
    auto alloc = [&](size_t bytes){ void* p = wsb + off; off += (bytes + 255) & ~(size_t)255; return p; };
    ushortT* Wswz  = (ushortT*)alloc(80u*8*512*2);     // Wall tiles 0..63, Wd tiles 64..79
    ushortT* Uswz  = (ushortT*)alloc(64u*8*512*2);
    ushortT* Eswz  = (ushortT*)alloc(16u*8*512*2);
    ushortT* Hswz  = (ushortT*)alloc(16u*8*512*2);
    ushortT* TWswz = (ushortT*)alloc(16u*8*512*2);     // time_w (only q=0,1 slots used)
    ushortT* W1swz = (ushortT*)alloc(4u*8*512*2);      // w1_w rows 256..511 (4 tiles)
    ushortT* TFT   = (ushortT*)alloc((size_t)16*SEQ*1024*2);   // 6.6 MB
    ushortT* X     = (ushortT*)alloc((size_t)NB*SEQ*256*2);    // 26.2 MB (reused as GENX)
    ushortT* XG    = (ushortT*)alloc((size_t)16*SEQ*16384*2);  // 100 MB
    ushortT* HS    = (ushortT*)alloc((size_t)NB*SEQ*256*2);    // 26.2 MB (also input bf16 staging)
    ushortT* EK    = (ushortT*)alloc((size_t)NB*256*2);
    float*  MAXH1  = (float*)alloc((size_t)NB*256*4);
    float*  MAXH2  = (float*)alloc((size_t)NB*256*4);
    float*  EKW    = (float*)alloc((size_t)NB*64*4);
    float*  W1P    = (float*)alloc((size_t)NB*SEQ*64*4);       // 13.1 MB
    unsigned* XBUF = (unsigned*)alloc((size_t)32*2*16*128*4);  // 512 KB pair-exchange {h,c} u32
    unsigned* FLAGS= (unsigned*)alloc((size_t)32*8*16*4);      // 16 KB, 64B-strided per-wave flags

    float* outp = (float*)d_out;
    // outputs 2,3 are pass-throughs (predicted_noise, normal_noise), f32
    hipMemcpyAsync(outp + 1024,       pn, NSZ*4, hipMemcpyDeviceToDevice, stream);
    hipMemcpyAsync(outp + 1024 + NSZ, nn, NSZ*4, hipMemcpyDeviceToDevice, stream);

    k_zeroflags<<<16, 256, 0, stream>>>(FLAGS);
    k_swizzle<<<dim3(64,8), 64, 0, stream>>>(Wall_w, 1024, Wswz, 0);
    k_swizzle<<<dim3(16,8), 64, 0, stream>>>(Wd_w,    256, Wswz, 64);
    k_swizzle<<<dim3(64,8), 64, 0, stream>>>(Uall_w, 1024, Uswz, 0);
    k_swizzle<<<dim3(16,8), 64, 0, stream>>>(emb2_w,  256, Eswz, 0);
    k_swizzle<<<dim3(16,8), 64, 0, stream>>>(whk_w,   256, Hswz, 0);
    k_swizzle<<<dim3(16,2), 64, 0, stream>>>(time_w,  256, TWswz, 0);  // K=64 → q<2
    k_swizzle<<<dim3(4,8),  64, 0, stream>>>(w1_w + 256*64, 64, W1swz, 0);

    k_tft<<<3200, 64, 0, stream>>>(seq_time, sel_w, sel_b, TFT);
    k_cvt<<<12800, 256, 0, stream>>>(input_seqs, HS);          // f32 input → bf16 (staged in HS)
    k_gemm256<<<3200, 512, 0, stream>>>(HS, Eswz, emb2_b, X);
    k_ekcopy<<<256, 64, 0, stream>>>(X, EK);
    k_ekw<<<256, 64, 0, stream>>>(EK, w1_w, w1_b, EKW);
    k_gemmgates<<<3200, 512, 0, stream>>>(X, Uswz, Wall_b, Uall_b, XG);
    k_scan<<<32, 512, SCAN_LDS, stream>>>(XG, TFT, Wswz, TWswz, Wd_b, time_b, HS, MAXH1, 1,
                                          XBUF, FLAGS, 0u);
    k_gemm256<<<3200, 512, 0, stream>>>(HS, Hswz, whk_b, HS);   // whk in-place (block-local rows)
    k_gemm64<<<3200, 256, 0, stream>>>(HS, W1swz, W1P);         // whk @ w1[256:512] (f32)
    k_attn<<<6400, 512, 0, stream>>>(EK, HS, EKW, W1P, w2_w, w2_b, nn, pn, X);  // genx → X region
    k_gemmgates<<<3200, 512, 0, stream>>>(X, Uswz, Wall_b, Uall_b, XG);
    k_scan<<<32, 512, SCAN_LDS, stream>>>(XG, TFT, Wswz, TWswz, Wd_b, time_b, HS, MAXH2, 0,
                                          XBUF, FLAGS, (unsigned)(SEQ-1));
    k_final<<<2, 512, 0, stream>>>(MAXH1, MAXH2, out_w, out_b, outp);
}